// Round 1
// baseline (1408.078 us; speedup 1.0000x reference)
//
#include <hip/hip_runtime.h>
#include <cmath>

typedef unsigned short u16;
typedef __attribute__((ext_vector_type(8))) __bf16 bf16x8;
typedef __attribute__((ext_vector_type(4))) float f32x4;

#define DEV static __device__ __forceinline__

DEV float b2f(u16 u){ union{unsigned i; float f;} v; v.i=((unsigned)u)<<16; return v.f; }
DEV u16 f2b(float f){ union{float f; unsigned i;} v; v.f=f; unsigned r = v.i + 0x7FFFu + ((v.i>>16)&1u); return (u16)(r>>16); }

#define GLL(g,l) __builtin_amdgcn_global_load_lds((const __attribute__((address_space(1))) void*)(g), (__attribute__((address_space(3))) void*)(l), 16, 0, 0)

// ---------------- tiny utility kernels ----------------
__global__ void k_zero(float* p, int n){ int i = blockIdx.x*256+threadIdx.x; if(i<n) p[i]=0.f; }

__global__ void k_cvt(const float* __restrict__ s, u16* __restrict__ d, int n){
  int i = blockIdx.x*256 + threadIdx.x; if (i<n) d[i] = f2b(s[i]);
}

// ---------------- GN stats on original [B,C,T] layout ----------------
// grid: B*32 blocks; block (b,g) reduces its contiguous chunk of n = chpg*8192 floats
__global__ void k_stats_ct(const float* __restrict__ x, float* __restrict__ stat, int n){
  const long base = (long)blockIdx.x * n;
  float s=0.f, s2=0.f;
  const float4* xp = (const float4*)(x+base);
  const int n4 = n>>2;
  for (int i=threadIdx.x; i<n4; i+=256){
    float4 v = xp[i];
    s  += v.x+v.y+v.z+v.w;
    s2 += v.x*v.x+v.y*v.y+v.z*v.z+v.w*v.w;
  }
  __shared__ float a[256], a2[256];
  a[threadIdx.x]=s; a2[threadIdx.x]=s2;
  __syncthreads();
  for (int off=128; off>0; off>>=1){
    if (threadIdx.x < off){ a[threadIdx.x]+=a[threadIdx.x+off]; a2[threadIdx.x]+=a2[threadIdx.x+off]; }
    __syncthreads();
  }
  if (threadIdx.x==0){
    const float mu = a[0]/n;
    const float var = a2[0]/n - mu*mu;
    stat[blockIdx.x*2]   = mu;
    stat[blockIdx.x*2+1] = rsqrtf(var + 1e-5f);
  }
}

// ---------------- transpose [B,C,T] -> [B,T,C]; write normalized bf16 (+ optionally raw fp32) ----
template<bool WF32>
__global__ void k_trans(const float* __restrict__ src, float* __restrict__ dstF,
                        u16* __restrict__ dstB, const float* __restrict__ stat,
                        const float* __restrict__ gw, const float* __restrict__ bw,
                        int C, int chsh){
  const int b = blockIdx.z;
  const int t0 = blockIdx.x*64, c0 = blockIdx.y*64;
  __shared__ float tile[64][65];
  #pragma unroll
  for (int p=0;p<4;p++){
    const int cc = (threadIdx.x>>4) + p*16, tt = (threadIdx.x&15)*4;
    const float4 v = *(const float4*)&src[((long)b*C + c0+cc)*8192 + t0+tt];
    tile[cc][tt+0]=v.x; tile[cc][tt+1]=v.y; tile[cc][tt+2]=v.z; tile[cc][tt+3]=v.w;
  }
  __syncthreads();
  #pragma unroll
  for (int p=0;p<4;p++){
    const int tt = (threadIdx.x>>4) + p*16, c4 = (threadIdx.x&15)*4;
    float raw[4]; u16 nbi[4];
    #pragma unroll
    for (int j=0;j<4;j++){
      raw[j] = tile[c4+j][tt];
      const int c = c0+c4+j, gr = c>>chsh;
      const float mu = stat[(b*32+gr)*2], rs = stat[(b*32+gr)*2+1];
      nbi[j] = f2b((raw[j]-mu)*rs*gw[c]+bw[c]);
    }
    const long db = ((long)b*8192 + t0+tt)*C + c0+c4;
    ushort4 nb; nb.x=nbi[0]; nb.y=nbi[1]; nb.z=nbi[2]; nb.w=nbi[3];
    *(ushort4*)&dstB[db] = nb;
    if (WF32){ float4 rv = {raw[0],raw[1],raw[2],raw[3]}; *(float4*)&dstF[db] = rv; }
  }
}

// ---------------- MFMA GEMM: out[t,o] = sum_k A[t,k]*W[o,k]  (A,W bf16; acc fp32) ----------------
template<bool OUTB, bool BIAS, bool SILU, bool RES>
__global__ __launch_bounds__(256,2) void k_gemm(
    const u16* __restrict__ A, const u16* __restrict__ W,
    float* __restrict__ outF, u16* __restrict__ outB,
    const float* __restrict__ bias, const float* __restrict__ res,
    int K, int O)
{
  __shared__ u16 As[128*64];
  __shared__ u16 Ws[128*64];
  const int tid = threadIdx.x;
  const int wv = tid>>6, lane = tid&63;
  const long t0 = (long)blockIdx.y*128;
  const int o0 = blockIdx.x*128;
  const int wt = (wv>>1)*64, wo = (wv&1)*64;
  const int lr = lane>>3, lc = (lane&7)*8;
  f32x4 acc[4][4] = {};
  for (int kc = 0; kc < K; kc += 64){
    #pragma unroll
    for (int it = 0; it < 4; ++it){
      const int r = wv*32 + it*8;
      GLL(A + (t0 + r + lr)*(long)K + kc + lc, &As[r*64]);
      GLL(W + (long)(o0 + r + lr)*K + kc + lc, &Ws[r*64]);
    }
    __syncthreads();
    #pragma unroll
    for (int ks=0; ks<2; ++ks){
      const int kb = ks*32 + (lane>>4)*8;
      bf16x8 af[4], bfr[4];
      #pragma unroll
      for (int i=0;i<4;i++) af[i]  = *(const bf16x8*)&As[(wt + i*16 + (lane&15))*64 + kb];
      #pragma unroll
      for (int j=0;j<4;j++) bfr[j] = *(const bf16x8*)&Ws[(wo + j*16 + (lane&15))*64 + kb];
      #pragma unroll
      for (int i=0;i<4;i++)
        #pragma unroll
        for (int j=0;j<4;j++)
          acc[i][j] = __builtin_amdgcn_mfma_f32_16x16x32_bf16(af[i], bfr[j], acc[i][j], 0, 0, 0);
    }
    __syncthreads();
  }
  const int q = lane>>4, cc = lane&15;
  #pragma unroll
  for (int j=0;j<4;j++){
    const int o = o0 + wo + j*16 + cc;
    const float bv = BIAS ? bias[o] : 0.f;
    #pragma unroll
    for (int i=0;i<4;i++){
      const long tb = t0 + wt + i*16 + q*4;
      #pragma unroll
      for (int r=0;r<4;r++){
        float v = acc[i][j][r] + bv;
        if (SILU) v = v * (1.f/(1.f + __expf(-v)));
        const long idx = (tb + r)*(long)O + o;
        if (RES) v += res[idx];
        if (OUTB) outB[idx] = f2b(v); else outF[idx] = v;
      }
    }
  }
}

// ---------------- k-softmax denominator: sums[b,c] = sum_t exp(k[b,t,c]) ----------------
__global__ void k_ksum(const u16* __restrict__ kp, float* __restrict__ sums, int stride, int koff){
  const int b = blockIdx.x>>5, seg = blockIdx.x&31;
  const int c = threadIdx.x;
  const long base = ((long)b*8192 + seg*256)*stride + koff + c;
  float s=0.f;
  for (int t=0;t<256;t++) s += __expf(b2f(kp[base + (long)t*stride]));
  atomicAdd(&sums[b*256+c], s);
}

// ---------------- ctx partials: part[b,seg, h*1024+d*32+e] = sum_{t in seg} exp(k[t,hd]) * v[t,he] ----
__global__ void k_ctx(const u16* __restrict__ kvp, float* __restrict__ part,
                      int stride, int koff, int voff){
  const int tid = threadIdx.x;
  const int b = blockIdx.x >> 6, seg = blockIdx.x & 63;
  const int h = tid>>5, d = tid&31;
  __shared__ u16 kb[16][256];
  __shared__ u16 vb[16][256];
  float acc[32];
  #pragma unroll
  for (int e=0;e<32;e++) acc[e]=0.f;
  const long rb = ((long)b*8192 + seg*128)*stride;
  for (int tc=0; tc<128; tc+=16){
    #pragma unroll
    for (int p=0;p<4;p++){
      const int L = p*256 + tid;
      const int row = L>>6, q8 = L&63;
      const long src = rb + (long)(tc+row)*stride + (q8<32 ? koff + q8*8 : voff + (q8-32)*8);
      uint4 val = *(const uint4*)(kvp + src);
      u16* dst = (q8<32) ? &kb[row][q8*8] : &vb[row][(q8-32)*8];
      *(uint4*)dst = val;
    }
    __syncthreads();
    #pragma unroll
    for (int r=0;r<16;r++){
      const float kpv = __expf(b2f(kb[r][h*32+d]));
      #pragma unroll
      for (int e=0;e<32;e++) acc[e] += kpv * b2f(vb[r][h*32+e]);
    }
    __syncthreads();
  }
  const long pb = (long)blockIdx.x*8192 + (long)tid*32;
  #pragma unroll
  for (int e=0;e<32;e++) part[pb+e] = acc[e];
}

// ---------------- ctx reduce + normalize by k-softmax sum ----------------
__global__ void k_ctxred(const float* __restrict__ part, const float* __restrict__ sums,
                         float* __restrict__ ctx){
  const int i = blockIdx.x*256 + threadIdx.x;   // 65536 outputs
  const int b = i>>13, idx = i&8191;
  float s=0.f;
  for (int g2=0; g2<64; g2++) s += part[((long)(b*64+g2))*8192 + idx];
  ctx[i] = s / sums[b*256 + (idx>>5)];
}

// ---------------- attn out: out[t, h*32+e] = sum_d softmax_d(q)[d]*scale * ctx[h,d,e] ----------------
__global__ void k_attnout(const u16* __restrict__ q, const float* __restrict__ ctx,
                          u16* __restrict__ out, int stride, int qoff){
  const int b = blockIdx.x >> 8, t0 = (blockIdx.x & 255)*32;
  __shared__ float cs[8512];   // [h][d][e] strides 1064/33/1 -> conflict-free broadcast
  for (int i=threadIdx.x; i<8192; i+=256){
    const int h=i>>10, de=i&1023;
    cs[h*1064 + (de>>5)*33 + (de&31)] = ctx[(b<<13) + i];
  }
  __syncthreads();
  const int t = t0 + (threadIdx.x>>3), h = threadIdx.x&7;
  const u16* qp = q + ((long)b*8192 + t)*stride + qoff + h*32;
  uint4 qv[4];
  #pragma unroll
  for (int j=0;j<4;j++) qv[j] = ((const uint4*)qp)[j];
  const u16* qs = (const u16*)qv;
  float qe[32]; float ssum = 0.f;
  #pragma unroll
  for (int dd=0; dd<32; dd++){ qe[dd] = __expf(b2f(qs[dd])); ssum += qe[dd]; }
  const float inv = 0.17677669529663687f / ssum;   // scale = 32^-0.5
  float o[32];
  #pragma unroll
  for (int e=0;e<32;e++) o[e]=0.f;
  const float* ch = &cs[h*1064];
  #pragma unroll
  for (int dd=0; dd<32; dd++){
    const float w = qe[dd]*inv;
    #pragma unroll
    for (int e=0;e<32;e++) o[e] += w * ch[dd*33+e];
  }
  u16 ob[32];
  #pragma unroll
  for (int e=0;e<32;e++) ob[e] = f2b(o[e]);
  uint4* op = (uint4*)(out + ((long)b*8192 + t)*256 + h*32);
  const uint4* obv = (const uint4*)ob;
  #pragma unroll
  for (int j=0;j<4;j++) op[j] = obv[j];
}

// ---------------- GN stats on [B,T,256] layout via column partials + atomics ----------------
__global__ void k_stats_tc(const float* __restrict__ x, float* __restrict__ sums){
  const int b = blockIdx.x>>3, seg = blockIdx.x&7;
  const int c = threadIdx.x;
  const long base = ((long)b*8192 + seg*1024)*256 + c;
  float s=0.f, s2=0.f;
  for (int t=0;t<1024;t++){
    const float v = x[base + (long)t*256];
    s += v; s2 += v*v;
  }
  __shared__ float a[256], a2[256];
  a[c]=s; a2[c]=s2; __syncthreads();
  if ((c&7)==0){
    float u=0.f,u2=0.f;
    #pragma unroll
    for (int j=0;j<8;j++){ u+=a[c+j]; u2+=a2[c+j]; }
    atomicAdd(&sums[(b*32+(c>>3))*2],   u);
    atomicAdd(&sums[(b*32+(c>>3))*2+1], u2);
  }
}

// ---------------- x_new = GN(conv)*g+b + x  (in-place on residual stream) ----------------
__global__ void k_gnres(const float* __restrict__ conv, float* __restrict__ xr,
                        const float* __restrict__ sums, const float* __restrict__ g,
                        const float* __restrict__ bt){
  const long i4 = (long)blockIdx.x*256 + threadIdx.x;
  const int b = (int)(i4 >> 19);
  const int c0 = (int)((i4<<2) & 255);
  float4 cv = ((const float4*)conv)[i4];
  float4 rv = ((const float4*)xr)[i4];
  float ci[4] = {cv.x,cv.y,cv.z,cv.w};
  float ri[4] = {rv.x,rv.y,rv.z,rv.w};
  float ov[4];
  #pragma unroll
  for (int j=0;j<4;j++){
    const int c = c0+j, gr = c>>3;
    const float s = sums[(b*32+gr)*2], s2 = sums[(b*32+gr)*2+1];
    const float mu = s*(1.f/65536.f);
    const float rs = rsqrtf(s2*(1.f/65536.f) - mu*mu + 1e-5f);
    ov[j] = (ci[j]-mu)*rs*g[c] + bt[c] + ri[j];
  }
  float4 o4 = {ov[0],ov[1],ov[2],ov[3]};
  ((float4*)xr)[i4] = o4;
}

// ---------------- bf16 normalized copy: h = GN(x)*g+b ----------------
__global__ void k_gnapply(const float* __restrict__ x, u16* __restrict__ o,
                          const float* __restrict__ sums, const float* __restrict__ g,
                          const float* __restrict__ bt){
  const long i4 = (long)blockIdx.x*256 + threadIdx.x;
  const int b = (int)(i4 >> 19);
  const int c0 = (int)((i4<<2) & 255);
  float4 v = ((const float4*)x)[i4];
  float vi[4] = {v.x,v.y,v.z,v.w};
  u16 obi[4];
  #pragma unroll
  for (int j=0;j<4;j++){
    const int c = c0+j, gr=c>>3;
    const float s = sums[(b*32+gr)*2], s2 = sums[(b*32+gr)*2+1];
    const float mu = s*(1.f/65536.f);
    const float rs = rsqrtf(s2*(1.f/65536.f)-mu*mu+1e-5f);
    obi[j] = f2b((vi[j]-mu)*rs*g[c]+bt[c]);
  }
  ushort4 ob; ob.x=obi[0]; ob.y=obi[1]; ob.z=obi[2]; ob.w=obi[3];
  ((ushort4*)o)[i4] = ob;
}

// ---------------- final transpose [B,T,256] -> [B,256,T] ----------------
__global__ void k_final(const float* __restrict__ y, float* __restrict__ out){
  const int b = blockIdx.z;
  const int t0 = blockIdx.x*64, c0 = blockIdx.y*64;
  __shared__ float tile[64][65];
  #pragma unroll
  for (int p=0;p<4;p++){
    const int tt = (threadIdx.x>>4) + p*16, c4 = (threadIdx.x&15)*4;
    const float4 v = *(const float4*)&y[((long)b*8192 + t0+tt)*256 + c0+c4];
    tile[c4+0][tt]=v.x; tile[c4+1][tt]=v.y; tile[c4+2][tt]=v.z; tile[c4+3][tt]=v.w;
  }
  __syncthreads();
  #pragma unroll
  for (int p=0;p<4;p++){
    const int cc = (threadIdx.x>>4) + p*16, t4 = (threadIdx.x&15)*4;
    float4 v = {tile[cc][t4], tile[cc][t4+1], tile[cc][t4+2], tile[cc][t4+3]};
    *(float4*)&out[((long)b*256 + c0+cc)*8192 + t0+t4] = v;
  }
}

extern "C" void kernel_launch(void* const* d_in, const int* in_sizes, int n_in,
                              void* d_out, int out_size, void* d_ws, size_t ws_size,
                              hipStream_t stream){
  (void)in_sizes; (void)n_in; (void)out_size; (void)ws_size;
  const float* x   = (const float*)d_in[0];
  const float* c   = (const float*)d_in[1];
  const float* W_qkv=(const float*)d_in[2];
  const float* W_so =(const float*)d_in[3];
  const float* b_so =(const float*)d_in[4];
  const float* sa_g =(const float*)d_in[5];
  const float* sa_b =(const float*)d_in[6];
  const float* W_cq =(const float*)d_in[7];
  const float* W_ckv=(const float*)d_in[8];
  const float* W_co =(const float*)d_in[9];
  const float* b_co =(const float*)d_in[10];
  const float* ca_g =(const float*)d_in[11];
  const float* ca_b =(const float*)d_in[12];
  const float* W_m1 =(const float*)d_in[13];
  const float* b_m1 =(const float*)d_in[14];
  const float* W_m2 =(const float*)d_in[15];
  const float* b_m2 =(const float*)d_in[16];
  const float* nm_g =(const float*)d_in[17];
  const float* nm_b =(const float*)d_in[18];
  const float* nm1_g=(const float*)d_in[19];
  const float* nm1_b=(const float*)d_in[20];
  const float* nm2_g=(const float*)d_in[21];
  const float* nm2_b=(const float*)d_in[22];
  const float* nm3_g=(const float*)d_in[23];
  const float* nm3_b=(const float*)d_in[24];
  float* out = (float*)d_out;

  char* ws = (char*)d_ws;
  const size_t MB = 1024ull*1024ull;
  u16* wbf  = (u16*)ws;
  u16* wQKV = wbf;
  u16* wSO  = wbf + 196608;
  u16* wCQ  = wbf + 262144;
  u16* wCKV = wbf + 327680;
  u16* wCO  = wbf + 589824;
  u16* wM1  = wbf + 655360;
  u16* wM2  = wbf + 819200;
  float* stats = (float*)(ws + 2*MB);
  float* xstat = stats;
  float* cstat = stats + 512;
  float* so_sum= stats + 1024;
  float* x1_sum= stats + 1536;
  float* co_sum= stats + 2048;
  float* x2_sum= stats + 2560;
  float* ksumS = stats + 4096;
  float* ksumC = stats + 6144;
  float* ctxb  = stats + 8192;
  float* xT    = (float*)(ws + 4*MB);     // [65536,256] fp32, doubles as residual stream (in-place)
  u16*   hbf   = (u16*)(ws + 68*MB);      // [65536,256] bf16 normalized
  u16*   cnbf  = (u16*)(ws + 100*MB);     // [65536,512] bf16 normalized c
  u16*   qkvb  = (u16*)(ws + 164*MB);     // [65536,768] bf16 (later: cross-q [.,256]; later: mlp [.,640])
  u16*   kvb   = (u16*)(ws + 196*MB);     // [65536,512] bf16 cross kv
  u16*   attno = (u16*)(ws + 260*MB);     // [65536,256] bf16
  float* convo = (float*)(ws + 292*MB);   // [65536,256] fp32
  float* part  = (float*)(ws + 356*MB);   // [8][64][8192] fp32 ctx partials (16MB)

  k_zero<<<32,256,0,stream>>>(stats, 8192);
  k_cvt<<<768,256,0,stream>>>(W_qkv, wQKV, 196608);
  k_cvt<<<256,256,0,stream>>>(W_so,  wSO,  65536);
  k_cvt<<<256,256,0,stream>>>(W_cq,  wCQ,  65536);
  k_cvt<<<1024,256,0,stream>>>(W_ckv, wCKV, 262144);
  k_cvt<<<256,256,0,stream>>>(W_co,  wCO,  65536);
  k_cvt<<<640,256,0,stream>>>(W_m1,  wM1,  163840);
  k_cvt<<<640,256,0,stream>>>(W_m2,  wM2,  163840);

  // ---- stage 1: self linear attention ----
  k_stats_ct<<<256,256,0,stream>>>(x, xstat, 8*8192);
  k_stats_ct<<<256,256,0,stream>>>(c, cstat, 16*8192);
  k_trans<true ><<<dim3(128,4,8),256,0,stream>>>(x, xT, hbf, xstat, nm_g, nm_b, 256, 3);
  k_trans<false><<<dim3(128,8,8),256,0,stream>>>(c, nullptr, cnbf, cstat, nm3_g, nm3_b, 512, 4);
  k_gemm<true,false,false,false><<<dim3(6,512),256,0,stream>>>(hbf, wQKV, nullptr, qkvb, nullptr, nullptr, 256, 768);
  k_ksum<<<256,256,0,stream>>>(qkvb, ksumS, 768, 256);
  k_ctx<<<512,256,0,stream>>>(qkvb, part, 768, 256, 512);
  k_ctxred<<<256,256,0,stream>>>(part, ksumS, ctxb);
  k_attnout<<<2048,256,0,stream>>>(qkvb, ctxb, attno, 768, 0);
  k_gemm<false,true,false,false><<<dim3(2,512),256,0,stream>>>(attno, wSO, convo, nullptr, b_so, nullptr, 256, 256);
  k_stats_tc<<<64,256,0,stream>>>(convo, so_sum);
  k_gnres<<<16384,256,0,stream>>>(convo, xT, so_sum, sa_g, sa_b);

  // ---- stage 2: cross linear attention ----
  k_stats_tc<<<64,256,0,stream>>>(xT, x1_sum);
  k_gnapply<<<16384,256,0,stream>>>(xT, hbf, x1_sum, nm1_g, nm1_b);
  k_gemm<true,false,false,false><<<dim3(2,512),256,0,stream>>>(hbf, wCQ, nullptr, qkvb, nullptr, nullptr, 256, 256);
  k_gemm<true,false,false,false><<<dim3(4,512),256,0,stream>>>(cnbf, wCKV, nullptr, kvb, nullptr, nullptr, 512, 512);
  k_ksum<<<256,256,0,stream>>>(kvb, ksumC, 512, 0);
  k_ctx<<<512,256,0,stream>>>(kvb, part, 512, 0, 256);
  k_ctxred<<<256,256,0,stream>>>(part, ksumC, ctxb);
  k_attnout<<<2048,256,0,stream>>>(qkvb, ctxb, attno, 256, 0);
  k_gemm<false,true,false,false><<<dim3(2,512),256,0,stream>>>(attno, wCO, convo, nullptr, b_co, nullptr, 256, 256);
  k_stats_tc<<<64,256,0,stream>>>(convo, co_sum);
  k_gnres<<<16384,256,0,stream>>>(convo, xT, co_sum, ca_g, ca_b);

  // ---- stage 3: SiLU MLP ----
  k_stats_tc<<<64,256,0,stream>>>(xT, x2_sum);
  k_gnapply<<<16384,256,0,stream>>>(xT, hbf, x2_sum, nm2_g, nm2_b);
  k_gemm<true,true,true,false><<<dim3(5,512),256,0,stream>>>(hbf, wM1, nullptr, qkvb, b_m1, nullptr, 256, 640);
  k_gemm<false,true,false,true><<<dim3(2,512),256,0,stream>>>(qkvb, wM2, convo, nullptr, b_m2, xT, 640, 256);
  k_final<<<dim3(128,4,8),256,0,stream>>>(convo, out);
}

// Round 2
// 1310.134 us; speedup vs baseline: 1.0748x; 1.0748x over previous
//
#include <hip/hip_runtime.h>
#include <cmath>

typedef unsigned short u16;
typedef __attribute__((ext_vector_type(8))) __bf16 bf16x8;
typedef __attribute__((ext_vector_type(4))) float f32x4;

#define DEV static __device__ __forceinline__

DEV float b2f(u16 u){ union{unsigned i; float f;} v; v.i=((unsigned)u)<<16; return v.f; }
DEV u16 f2b(float f){ union{float f; unsigned i;} v; v.f=f; unsigned r = v.i + 0x7FFFu + ((v.i>>16)&1u); return (u16)(r>>16); }

#define GLL(g,l) __builtin_amdgcn_global_load_lds((const __attribute__((address_space(1))) void*)(g), (__attribute__((address_space(3))) void*)(l), 16, 0, 0)

// ---------------- tiny utility kernels ----------------
__global__ void k_zero(float* p, int n){ int i = blockIdx.x*256+threadIdx.x; if(i<n) p[i]=0.f; }

// all weights -> bf16, one launch. dest offsets fixed.
__global__ void k_cvtall(const float* __restrict__ s0,const float* __restrict__ s1,
                         const float* __restrict__ s2,const float* __restrict__ s3,
                         const float* __restrict__ s4,const float* __restrict__ s5,
                         const float* __restrict__ s6, u16* __restrict__ d){
  int i = blockIdx.x*256 + threadIdx.x;
  if (i >= 983040) return;
  const float* s; int off;
  if      (i < 196608){ s=s0; off=0; }
  else if (i < 262144){ s=s1; off=196608; }
  else if (i < 327680){ s=s2; off=262144; }
  else if (i < 589824){ s=s3; off=327680; }
  else if (i < 655360){ s=s4; off=589824; }
  else if (i < 819200){ s=s5; off=655360; }
  else                { s=s6; off=819200; }
  d[i] = f2b(s[i-off]);
}

// ---------------- GN stats on original [B,C,T] layout (x and c in one launch) ----------------
__global__ void k_stats_ct(const float* __restrict__ x, const float* __restrict__ c,
                           float* __restrict__ statx, float* __restrict__ statc){
  const bool isc = blockIdx.x >= 256;
  const int blk = isc ? blockIdx.x - 256 : blockIdx.x;
  const int n = isc ? 131072 : 65536;
  const float* src = isc ? c : x;
  float* stat = isc ? statc : statx;
  const long base = (long)blk * n;
  float s=0.f, s2=0.f;
  const float4* xp = (const float4*)(src+base);
  const int n4 = n>>2;
  for (int i=threadIdx.x; i<n4; i+=256){
    float4 v = xp[i];
    s  += v.x+v.y+v.z+v.w;
    s2 += v.x*v.x+v.y*v.y+v.z*v.z+v.w*v.w;
  }
  __shared__ float a[256], a2[256];
  a[threadIdx.x]=s; a2[threadIdx.x]=s2;
  __syncthreads();
  for (int off=128; off>0; off>>=1){
    if (threadIdx.x < off){ a[threadIdx.x]+=a[threadIdx.x+off]; a2[threadIdx.x]+=a2[threadIdx.x+off]; }
    __syncthreads();
  }
  if (threadIdx.x==0){
    const float mu = a[0]/n;
    const float var = a2[0]/n - mu*mu;
    stat[blk*2]   = mu;
    stat[blk*2+1] = rsqrtf(var + 1e-5f);
  }
}

// ---------------- transpose [B,C,T] -> [B,T,C]; write normalized bf16 (+ optionally raw fp32) ----
template<bool WF32>
__global__ void k_trans(const float* __restrict__ src, float* __restrict__ dstF,
                        u16* __restrict__ dstB, const float* __restrict__ stat,
                        const float* __restrict__ gw, const float* __restrict__ bw,
                        int C, int chsh){
  const int b = blockIdx.z;
  const int t0 = blockIdx.x*64, c0 = blockIdx.y*64;
  __shared__ float tile[64][65];
  #pragma unroll
  for (int p=0;p<4;p++){
    const int cc = (threadIdx.x>>4) + p*16, tt = (threadIdx.x&15)*4;
    const float4 v = *(const float4*)&src[((long)b*C + c0+cc)*8192 + t0+tt];
    tile[cc][tt+0]=v.x; tile[cc][tt+1]=v.y; tile[cc][tt+2]=v.z; tile[cc][tt+3]=v.w;
  }
  __syncthreads();
  #pragma unroll
  for (int p=0;p<4;p++){
    const int tt = (threadIdx.x>>4) + p*16, c4 = (threadIdx.x&15)*4;
    float raw[4]; u16 nbi[4];
    #pragma unroll
    for (int j=0;j<4;j++){
      raw[j] = tile[c4+j][tt];
      const int c = c0+c4+j, gr = c>>chsh;
      const float mu = stat[(b*32+gr)*2], rs = stat[(b*32+gr)*2+1];
      nbi[j] = f2b((raw[j]-mu)*rs*gw[c]+bw[c]);
    }
    const long db = ((long)b*8192 + t0+tt)*C + c0+c4;
    ushort4 nb; nb.x=nbi[0]; nb.y=nbi[1]; nb.z=nbi[2]; nb.w=nbi[3];
    *(ushort4*)&dstB[db] = nb;
    if (WF32){ float4 rv = {raw[0],raw[1],raw[2],raw[3]}; *(float4*)&dstF[db] = rv; }
  }
}

// ---------------- MFMA GEMM: out[t,o] = sum_k A[t,k]*W[o,k]  (A,W bf16; acc fp32) ----------------
// STATS: accumulate per-(b,group) sum/sumsq of the written values into stat[] (raw sums)
template<bool OUTB, bool BIAS, bool SILU, bool RES, bool STATS>
__global__ __launch_bounds__(256,2) void k_gemm(
    const u16* __restrict__ A, const u16* __restrict__ W,
    float* __restrict__ outF, u16* __restrict__ outB,
    const float* __restrict__ bias, const float* __restrict__ res,
    float* __restrict__ stat, int K, int O)
{
  __shared__ u16 As[128*64];
  __shared__ u16 Ws[128*64];
  __shared__ float sb[128][2];
  const int tid = threadIdx.x;
  const int wv = tid>>6, lane = tid&63;
  const long t0 = (long)blockIdx.y*128;
  const int o0 = blockIdx.x*128;
  const int wt = (wv>>1)*64, wo = (wv&1)*64;
  const int lr = lane>>3, lc = (lane&7)*8;
  f32x4 acc[4][4] = {};
  for (int kc = 0; kc < K; kc += 64){
    #pragma unroll
    for (int it = 0; it < 4; ++it){
      const int r = wv*32 + it*8;
      GLL(A + (t0 + r + lr)*(long)K + kc + lc, &As[r*64]);
      GLL(W + (long)(o0 + r + lr)*K + kc + lc, &Ws[r*64]);
    }
    __syncthreads();
    #pragma unroll
    for (int ks=0; ks<2; ++ks){
      const int kb = ks*32 + (lane>>4)*8;
      bf16x8 af[4], bfr[4];
      #pragma unroll
      for (int i=0;i<4;i++) af[i]  = *(const bf16x8*)&As[(wt + i*16 + (lane&15))*64 + kb];
      #pragma unroll
      for (int j=0;j<4;j++) bfr[j] = *(const bf16x8*)&Ws[(wo + j*16 + (lane&15))*64 + kb];
      #pragma unroll
      for (int i=0;i<4;i++)
        #pragma unroll
        for (int j=0;j<4;j++)
          acc[i][j] = __builtin_amdgcn_mfma_f32_16x16x32_bf16(af[i], bfr[j], acc[i][j], 0, 0, 0);
    }
    __syncthreads();
  }
  if (STATS){
    if (tid < 128){ sb[tid][0]=0.f; sb[tid][1]=0.f; }
    __syncthreads();
  }
  const int q = lane>>4, cc = lane&15;
  #pragma unroll
  for (int j=0;j<4;j++){
    const int o = o0 + wo + j*16 + cc;
    const float bv = BIAS ? bias[o] : 0.f;
    float ts=0.f, ts2=0.f;
    #pragma unroll
    for (int i=0;i<4;i++){
      const long tb = t0 + wt + i*16 + q*4;
      #pragma unroll
      for (int r=0;r<4;r++){
        float v = acc[i][j][r] + bv;
        if (SILU) v = v * (1.f/(1.f + __expf(-v)));
        const long idx = (tb + r)*(long)O + o;
        if (RES) v += res[idx];
        if (STATS){ ts += v; ts2 += v*v; }
        if (OUTB) outB[idx] = f2b(v); else outF[idx] = v;
      }
    }
    if (STATS){
      const int ol = wo + j*16 + cc;
      atomicAdd(&sb[ol][0], ts);
      atomicAdd(&sb[ol][1], ts2);
    }
  }
  if (STATS){
    __syncthreads();
    if (tid < 16){
      float u=0.f, u2=0.f;
      #pragma unroll
      for (int j2=0;j2<8;j2++){ u += sb[tid*8+j2][0]; u2 += sb[tid*8+j2][1]; }
      const int bb = (int)(t0>>13);
      atomicAdd(&stat[(bb*32 + (o0>>3) + tid)*2],   u);
      atomicAdd(&stat[(bb*32 + (o0>>3) + tid)*2+1], u2);
    }
  }
}

// ---------------- ctx partials + fused k-softmax denominator ----------------
// part layout: [blk][e*256 + c], c = h*32+d  (coalesced wave stores)
__global__ void k_ctx(const u16* __restrict__ kvp, float* __restrict__ part,
                      float* __restrict__ ksum, int stride, int koff, int voff){
  const int tid = threadIdx.x;
  const int b = blockIdx.x >> 6, seg = blockIdx.x & 63;
  const int h = tid>>5, d = tid&31;
  __shared__ u16 kb[16][256];
  __shared__ u16 vb[16][256];
  float acc[32];
  #pragma unroll
  for (int e=0;e<32;e++) acc[e]=0.f;
  float ks = 0.f;
  const long rb = ((long)b*8192 + seg*128)*stride;
  for (int tc=0; tc<128; tc+=16){
    #pragma unroll
    for (int p=0;p<4;p++){
      const int L = p*256 + tid;
      const int row = L>>6, q8 = L&63;
      const long src = rb + (long)(tc+row)*stride + (q8<32 ? koff + q8*8 : voff + (q8-32)*8);
      uint4 val = *(const uint4*)(kvp + src);
      u16* dst = (q8<32) ? &kb[row][q8*8] : &vb[row][(q8-32)*8];
      *(uint4*)dst = val;
    }
    __syncthreads();
    #pragma unroll
    for (int r=0;r<16;r++){
      const float kpv = __expf(b2f(kb[r][h*32+d]));
      ks += kpv;
      #pragma unroll
      for (int e=0;e<32;e++) acc[e] += kpv * b2f(vb[r][h*32+e]);
    }
    __syncthreads();
  }
  float* pb = part + (long)blockIdx.x*8192;
  #pragma unroll
  for (int e=0;e<32;e++) pb[e*256 + tid] = acc[e];
  atomicAdd(&ksum[b*256 + tid], ks);
}

// ---------------- ctx reduce + normalize by k-softmax sum; ctx layout [b][e*256+c] ----------------
__global__ void k_ctxred(const float* __restrict__ part, const float* __restrict__ sums,
                         float* __restrict__ ctx){
  const int i = blockIdx.x*256 + threadIdx.x;   // 65536 outputs
  const int b = i>>13, r = i&8191;              // r = e*256 + c
  float s=0.f;
  for (int g2=0; g2<64; g2++) s += part[((long)(b*64+g2))*8192 + r];
  ctx[i] = s / sums[b*256 + (r&255)];
}

// ---------------- attn out: out[t, h*32+e] = sum_d softmax_d(q)[d]*scale * ctx[h,d,e] ----------------
__global__ void k_attnout(const u16* __restrict__ q, const float* __restrict__ ctx,
                          u16* __restrict__ out, int stride, int qoff){
  const int b = blockIdx.x >> 8, t0 = (blockIdx.x & 255)*32;
  __shared__ float cs[8512];   // [h][d][e] strides 1064/33/1 -> conflict-free broadcast
  for (int i=threadIdx.x; i<8192; i+=256){
    const int e=i>>8, cch=i&255;
    cs[(cch>>5)*1064 + (cch&31)*33 + e] = ctx[(b<<13) + i];
  }
  __syncthreads();
  const int t = t0 + (threadIdx.x>>3), h = threadIdx.x&7;
  const u16* qp = q + ((long)b*8192 + t)*stride + qoff + h*32;
  uint4 qv[4];
  #pragma unroll
  for (int j=0;j<4;j++) qv[j] = ((const uint4*)qp)[j];
  const u16* qs = (const u16*)qv;
  float qe[32]; float ssum = 0.f;
  #pragma unroll
  for (int dd=0; dd<32; dd++){ qe[dd] = __expf(b2f(qs[dd])); ssum += qe[dd]; }
  const float inv = 0.17677669529663687f / ssum;   // scale = 32^-0.5
  float o[32];
  #pragma unroll
  for (int e=0;e<32;e++) o[e]=0.f;
  const float* ch = &cs[h*1064];
  #pragma unroll
  for (int dd=0; dd<32; dd++){
    const float w = qe[dd]*inv;
    #pragma unroll
    for (int e=0;e<32;e++) o[e] += w * ch[dd*33+e];
  }
  u16 ob[32];
  #pragma unroll
  for (int e=0;e<32;e++) ob[e] = f2b(o[e]);
  uint4* op = (uint4*)(out + ((long)b*8192 + t)*256 + h*32);
  const uint4* obv = (const uint4*)ob;
  #pragma unroll
  for (int j=0;j<4;j++) op[j] = obv[j];
}

// ---------------- x_new = GN(conv)*g+b + x (in-place) + fused stats of x_new ----------------
// grid 1024: blk = b*128 + tseg; each block: 64 tokens (16 iters of 256 float4)
__global__ void k_gnres(const float* __restrict__ conv, float* __restrict__ xr,
                        const float* __restrict__ sums_in, float* __restrict__ sums_out,
                        const float* __restrict__ g, const float* __restrict__ bt){
  const int blk = blockIdx.x;
  const int b = blk>>7;
  const long base = (long)blk*4096;
  const int tid = threadIdx.x;
  const int c0 = (tid<<2)&255;
  const int gr = c0>>3;
  const float s = sums_in[(b*32+gr)*2], s2 = sums_in[(b*32+gr)*2+1];
  const float mu = s*(1.f/65536.f);
  const float rs = rsqrtf(s2*(1.f/65536.f) - mu*mu + 1e-5f);
  float gg[4], bb[4];
  #pragma unroll
  for (int j=0;j<4;j++){ gg[j] = g[c0+j]*rs; bb[j] = bt[c0+j] - mu*gg[j]; }
  float ts=0.f, ts2=0.f;
  for (int it=0; it<16; ++it){
    const long i4 = base + it*256 + tid;
    float4 cv = ((const float4*)conv)[i4];
    float4 rv = ((const float4*)xr)[i4];
    float ci[4] = {cv.x,cv.y,cv.z,cv.w};
    float ri[4] = {rv.x,rv.y,rv.z,rv.w};
    float ov[4];
    #pragma unroll
    for (int j=0;j<4;j++){
      ov[j] = ci[j]*gg[j] + bb[j] + ri[j];
      ts += ov[j]; ts2 += ov[j]*ov[j];
    }
    float4 o4 = {ov[0],ov[1],ov[2],ov[3]};
    ((float4*)xr)[i4] = o4;
  }
  __shared__ float grp[32][2];
  if (tid<32){ grp[tid][0]=0.f; grp[tid][1]=0.f; }
  __syncthreads();
  atomicAdd(&grp[gr][0], ts);
  atomicAdd(&grp[gr][1], ts2);
  __syncthreads();
  if (tid<32){
    atomicAdd(&sums_out[(b*32+tid)*2],   grp[tid][0]);
    atomicAdd(&sums_out[(b*32+tid)*2+1], grp[tid][1]);
  }
}

// ---------------- bf16 normalized copy: h = GN(x)*g+b ----------------
__global__ void k_gnapply(const float* __restrict__ x, u16* __restrict__ o,
                          const float* __restrict__ sums, const float* __restrict__ g,
                          const float* __restrict__ bt){
  const long i4 = (long)blockIdx.x*256 + threadIdx.x;
  const int b = (int)(i4 >> 19);
  const int c0 = (int)((i4<<2) & 255);
  float4 v = ((const float4*)x)[i4];
  float vi[4] = {v.x,v.y,v.z,v.w};
  u16 obi[4];
  #pragma unroll
  for (int j=0;j<4;j++){
    const int c = c0+j, gr=c>>3;
    const float s = sums[(b*32+gr)*2], s2 = sums[(b*32+gr)*2+1];
    const float mu = s*(1.f/65536.f);
    const float rs = rsqrtf(s2*(1.f/65536.f)-mu*mu+1e-5f);
    obi[j] = f2b((vi[j]-mu)*rs*g[c]+bt[c]);
  }
  ushort4 ob; ob.x=obi[0]; ob.y=obi[1]; ob.z=obi[2]; ob.w=obi[3];
  ((ushort4*)o)[i4] = ob;
}

// ---------------- final transpose [B,T,256] -> [B,256,T] ----------------
__global__ void k_final(const float* __restrict__ y, float* __restrict__ out){
  const int b = blockIdx.z;
  const int t0 = blockIdx.x*64, c0 = blockIdx.y*64;
  __shared__ float tile[64][65];
  #pragma unroll
  for (int p=0;p<4;p++){
    const int tt = (threadIdx.x>>4) + p*16, c4 = (threadIdx.x&15)*4;
    const float4 v = *(const float4*)&y[((long)b*8192 + t0+tt)*256 + c0+c4];
    tile[c4+0][tt]=v.x; tile[c4+1][tt]=v.y; tile[c4+2][tt]=v.z; tile[c4+3][tt]=v.w;
  }
  __syncthreads();
  #pragma unroll
  for (int p=0;p<4;p++){
    const int cc = (threadIdx.x>>4) + p*16, t4 = (threadIdx.x&15)*4;
    float4 v = {tile[cc][t4], tile[cc][t4+1], tile[cc][t4+2], tile[cc][t4+3]};
    *(float4*)&out[((long)b*256 + c0+cc)*8192 + t0+t4] = v;
  }
}

extern "C" void kernel_launch(void* const* d_in, const int* in_sizes, int n_in,
                              void* d_out, int out_size, void* d_ws, size_t ws_size,
                              hipStream_t stream){
  (void)in_sizes; (void)n_in; (void)out_size; (void)ws_size;
  const float* x   = (const float*)d_in[0];
  const float* c   = (const float*)d_in[1];
  const float* W_qkv=(const float*)d_in[2];
  const float* W_so =(const float*)d_in[3];
  const float* b_so =(const float*)d_in[4];
  const float* sa_g =(const float*)d_in[5];
  const float* sa_b =(const float*)d_in[6];
  const float* W_cq =(const float*)d_in[7];
  const float* W_ckv=(const float*)d_in[8];
  const float* W_co =(const float*)d_in[9];
  const float* b_co =(const float*)d_in[10];
  const float* ca_g =(const float*)d_in[11];
  const float* ca_b =(const float*)d_in[12];
  const float* W_m1 =(const float*)d_in[13];
  const float* b_m1 =(const float*)d_in[14];
  const float* W_m2 =(const float*)d_in[15];
  const float* b_m2 =(const float*)d_in[16];
  const float* nm_g =(const float*)d_in[17];
  const float* nm_b =(const float*)d_in[18];
  const float* nm1_g=(const float*)d_in[19];
  const float* nm1_b=(const float*)d_in[20];
  const float* nm2_g=(const float*)d_in[21];
  const float* nm2_b=(const float*)d_in[22];
  const float* nm3_g=(const float*)d_in[23];
  const float* nm3_b=(const float*)d_in[24];
  float* out = (float*)d_out;

  char* ws = (char*)d_ws;
  const size_t MB = 1024ull*1024ull;
  u16* wbf  = (u16*)ws;
  u16* wQKV = wbf;
  u16* wSO  = wbf + 196608;
  u16* wCQ  = wbf + 262144;
  u16* wCKV = wbf + 327680;
  u16* wCO  = wbf + 589824;
  u16* wM1  = wbf + 655360;
  u16* wM2  = wbf + 819200;
  float* stats = (float*)(ws + 2*MB);
  float* xstat = stats;
  float* cstat = stats + 512;
  float* so_sum= stats + 1024;
  float* x1_sum= stats + 1536;
  float* co_sum= stats + 2048;
  float* x2_sum= stats + 2560;
  float* ksumS = stats + 4096;
  float* ksumC = stats + 6144;
  float* ctxb  = stats + 8192;
  float* xT    = (float*)(ws + 4*MB);     // [65536,256] fp32 residual stream (in-place)
  u16*   hbf   = (u16*)(ws + 68*MB);      // [65536,256] bf16 normalized
  u16*   cnbf  = (u16*)(ws + 100*MB);     // [65536,512] bf16 normalized c
  u16*   qkvb  = (u16*)(ws + 164*MB);     // [65536,768] bf16 (reused: cross-q, mlp hidden)
  u16*   kvb   = (u16*)(ws + 196*MB);     // [65536,512] bf16 cross kv
  u16*   attno = (u16*)(ws + 260*MB);     // [65536,256] bf16
  float* convo = (float*)(ws + 292*MB);   // [65536,256] fp32
  float* part  = (float*)(ws + 356*MB);   // [512][8192] fp32 ctx partials (16MB)

  k_zero<<<32,256,0,stream>>>(stats, 8192);
  k_cvtall<<<3840,256,0,stream>>>(W_qkv, W_so, W_cq, W_ckv, W_co, W_m1, W_m2, wbf);

  // ---- stage 1: self linear attention ----
  k_stats_ct<<<512,256,0,stream>>>(x, c, xstat, cstat);
  k_trans<true ><<<dim3(128,4,8),256,0,stream>>>(x, xT, hbf, xstat, nm_g, nm_b, 256, 3);
  k_trans<false><<<dim3(128,8,8),256,0,stream>>>(c, nullptr, cnbf, cstat, nm3_g, nm3_b, 512, 4);
  k_gemm<true,false,false,false,false><<<dim3(6,512),256,0,stream>>>(hbf, wQKV, nullptr, qkvb, nullptr, nullptr, nullptr, 256, 768);
  k_ctx<<<512,256,0,stream>>>(qkvb, part, ksumS, 768, 256, 512);
  k_ctxred<<<256,256,0,stream>>>(part, ksumS, ctxb);
  k_attnout<<<2048,256,0,stream>>>(qkvb, ctxb, attno, 768, 0);
  k_gemm<false,true,false,false,true><<<dim3(2,512),256,0,stream>>>(attno, wSO, convo, nullptr, b_so, nullptr, so_sum, 256, 256);
  k_gnres<<<1024,256,0,stream>>>(convo, xT, so_sum, x1_sum, sa_g, sa_b);

  // ---- stage 2: cross linear attention ----
  k_gnapply<<<16384,256,0,stream>>>(xT, hbf, x1_sum, nm1_g, nm1_b);
  k_gemm<true,false,false,false,false><<<dim3(2,512),256,0,stream>>>(hbf, wCQ, nullptr, qkvb, nullptr, nullptr, nullptr, 256, 256);
  k_gemm<true,false,false,false,false><<<dim3(4,512),256,0,stream>>>(cnbf, wCKV, nullptr, kvb, nullptr, nullptr, nullptr, 512, 512);
  k_ctx<<<512,256,0,stream>>>(kvb, part, ksumC, 512, 0, 256);
  k_ctxred<<<256,256,0,stream>>>(part, ksumC, ctxb);
  k_attnout<<<2048,256,0,stream>>>(qkvb, ctxb, attno, 256, 0);
  k_gemm<false,true,false,false,true><<<dim3(2,512),256,0,stream>>>(attno, wCO, convo, nullptr, b_co, nullptr, co_sum, 256, 256);
  k_gnres<<<1024,256,0,stream>>>(convo, xT, co_sum, x2_sum, ca_g, ca_b);

  // ---- stage 3: SiLU MLP ----
  k_gnapply<<<16384,256,0,stream>>>(xT, hbf, x2_sum, nm2_g, nm2_b);
  k_gemm<true,true,true,false,false><<<dim3(5,512),256,0,stream>>>(hbf, wM1, nullptr, qkvb, b_m1, nullptr, nullptr, 256, 640);
  k_gemm<false,true,false,true,false><<<dim3(2,512),256,0,stream>>>(qkvb, wM2, convo, nullptr, b_m2, xT, nullptr, 640, 256);
  k_final<<<dim3(128,4,8),256,0,stream>>>(convo, out);
}

// Round 3
// 1044.063 us; speedup vs baseline: 1.3487x; 1.2548x over previous
//
#include <hip/hip_runtime.h>
#include <cmath>

typedef unsigned short u16;
typedef __attribute__((ext_vector_type(8))) __bf16 bf16x8;
typedef __attribute__((ext_vector_type(4))) float f32x4;

#define DEV static __device__ __forceinline__

DEV float b2f(u16 u){ union{unsigned i; float f;} v; v.i=((unsigned)u)<<16; return v.f; }
DEV u16 f2b(float f){ union{float f; unsigned i;} v; v.f=f; unsigned r = v.i + 0x7FFFu + ((v.i>>16)&1u); return (u16)(r>>16); }

#define GLL(g,l) __builtin_amdgcn_global_load_lds((const __attribute__((address_space(1))) void*)(g), (__attribute__((address_space(3))) void*)(l), 16, 0, 0)

// ---------------- tiny utility kernels ----------------
__global__ void k_zero(float* p, int n){ int i = blockIdx.x*256+threadIdx.x; if(i<n) p[i]=0.f; }

__global__ void k_cvtall(const float* __restrict__ s0,const float* __restrict__ s1,
                         const float* __restrict__ s2,const float* __restrict__ s3,
                         const float* __restrict__ s4,const float* __restrict__ s5,
                         const float* __restrict__ s6, u16* __restrict__ d){
  int i = blockIdx.x*256 + threadIdx.x;
  if (i >= 983040) return;
  const float* s; int off;
  if      (i < 196608){ s=s0; off=0; }
  else if (i < 262144){ s=s1; off=196608; }
  else if (i < 327680){ s=s2; off=262144; }
  else if (i < 589824){ s=s3; off=327680; }
  else if (i < 655360){ s=s4; off=589824; }
  else if (i < 819200){ s=s5; off=655360; }
  else                { s=s6; off=819200; }
  d[i] = f2b(s[i-off]);
}

// ---------------- GN stats on original [B,C,T] layout (x and c in one launch) ----------------
__global__ void k_stats_ct(const float* __restrict__ x, const float* __restrict__ c,
                           float* __restrict__ statx, float* __restrict__ statc){
  const bool isc = blockIdx.x >= 256;
  const int blk = isc ? blockIdx.x - 256 : blockIdx.x;
  const int n = isc ? 131072 : 65536;
  const float* src = isc ? c : x;
  float* stat = isc ? statc : statx;
  const long base = (long)blk * n;
  float s=0.f, s2=0.f;
  const float4* xp = (const float4*)(src+base);
  const int n4 = n>>2;
  for (int i=threadIdx.x; i<n4; i+=256){
    float4 v = xp[i];
    s  += v.x+v.y+v.z+v.w;
    s2 += v.x*v.x+v.y*v.y+v.z*v.z+v.w*v.w;
  }
  __shared__ float a[256], a2[256];
  a[threadIdx.x]=s; a2[threadIdx.x]=s2;
  __syncthreads();
  for (int off=128; off>0; off>>=1){
    if (threadIdx.x < off){ a[threadIdx.x]+=a[threadIdx.x+off]; a2[threadIdx.x]+=a2[threadIdx.x+off]; }
    __syncthreads();
  }
  if (threadIdx.x==0){
    const float mu = a[0]/n;
    const float var = a2[0]/n - mu*mu;
    stat[blk*2]   = mu;
    stat[blk*2+1] = rsqrtf(var + 1e-5f);
  }
}

// ---------------- transpose [B,C,T] -> [B,T,C]; write normalized bf16 (+ optionally raw fp32) ----
template<bool WF32>
__global__ void k_trans(const float* __restrict__ src, float* __restrict__ dstF,
                        u16* __restrict__ dstB, const float* __restrict__ stat,
                        const float* __restrict__ gw, const float* __restrict__ bw,
                        int C, int chsh){
  const int b = blockIdx.z;
  const int t0 = blockIdx.x*64, c0 = blockIdx.y*64;
  __shared__ float tile[64][65];
  #pragma unroll
  for (int p=0;p<4;p++){
    const int cc = (threadIdx.x>>4) + p*16, tt = (threadIdx.x&15)*4;
    const float4 v = *(const float4*)&src[((long)b*C + c0+cc)*8192 + t0+tt];
    tile[cc][tt+0]=v.x; tile[cc][tt+1]=v.y; tile[cc][tt+2]=v.z; tile[cc][tt+3]=v.w;
  }
  __syncthreads();
  #pragma unroll
  for (int p=0;p<4;p++){
    const int tt = (threadIdx.x>>4) + p*16, c4 = (threadIdx.x&15)*4;
    float raw[4]; u16 nbi[4];
    #pragma unroll
    for (int j=0;j<4;j++){
      raw[j] = tile[c4+j][tt];
      const int c = c0+c4+j, gr = c>>chsh;
      const float mu = stat[(b*32+gr)*2], rs = stat[(b*32+gr)*2+1];
      nbi[j] = f2b((raw[j]-mu)*rs*gw[c]+bw[c]);
    }
    const long db = ((long)b*8192 + t0+tt)*C + c0+c4;
    ushort4 nb; nb.x=nbi[0]; nb.y=nbi[1]; nb.z=nbi[2]; nb.w=nbi[3];
    *(ushort4*)&dstB[db] = nb;
    if (WF32){ float4 rv = {raw[0],raw[1],raw[2],raw[3]}; *(float4*)&dstF[db] = rv; }
  }
}

// ---------------- MFMA GEMM: out[t,o] = sum_k A[t,k]*W[o,k]  (A,W bf16; acc fp32) ----------------
template<bool OUTB, bool BIAS, bool SILU, bool RES, bool STATS>
__global__ __launch_bounds__(256,2) void k_gemm(
    const u16* __restrict__ A, const u16* __restrict__ W,
    float* __restrict__ outF, u16* __restrict__ outB,
    const float* __restrict__ bias, const float* __restrict__ res,
    float* __restrict__ stat, int K, int O)
{
  __shared__ u16 As[128*64];
  __shared__ u16 Ws[128*64];
  __shared__ float sb[128][2];
  const int tid = threadIdx.x;
  const int wv = tid>>6, lane = tid&63;
  const long t0 = (long)blockIdx.y*128;
  const int o0 = blockIdx.x*128;
  const int wt = (wv>>1)*64, wo = (wv&1)*64;
  const int lr = lane>>3, lc = (lane&7)*8;
  f32x4 acc[4][4] = {};
  for (int kc = 0; kc < K; kc += 64){
    #pragma unroll
    for (int it = 0; it < 4; ++it){
      const int r = wv*32 + it*8;
      GLL(A + (t0 + r + lr)*(long)K + kc + lc, &As[r*64]);
      GLL(W + (long)(o0 + r + lr)*K + kc + lc, &Ws[r*64]);
    }
    __syncthreads();
    #pragma unroll
    for (int ks=0; ks<2; ++ks){
      const int kb = ks*32 + (lane>>4)*8;
      bf16x8 af[4], bfr[4];
      #pragma unroll
      for (int i=0;i<4;i++) af[i]  = *(const bf16x8*)&As[(wt + i*16 + (lane&15))*64 + kb];
      #pragma unroll
      for (int j=0;j<4;j++) bfr[j] = *(const bf16x8*)&Ws[(wo + j*16 + (lane&15))*64 + kb];
      #pragma unroll
      for (int i=0;i<4;i++)
        #pragma unroll
        for (int j=0;j<4;j++)
          acc[i][j] = __builtin_amdgcn_mfma_f32_16x16x32_bf16(af[i], bfr[j], acc[i][j], 0, 0, 0);
    }
    __syncthreads();
  }
  if (STATS){
    if (tid < 128){ sb[tid][0]=0.f; sb[tid][1]=0.f; }
    __syncthreads();
  }
  const int q = lane>>4, cc = lane&15;
  #pragma unroll
  for (int j=0;j<4;j++){
    const int o = o0 + wo + j*16 + cc;
    const float bv = BIAS ? bias[o] : 0.f;
    float ts=0.f, ts2=0.f;
    #pragma unroll
    for (int i=0;i<4;i++){
      const long tb = t0 + wt + i*16 + q*4;
      #pragma unroll
      for (int r=0;r<4;r++){
        float v = acc[i][j][r] + bv;
        if (SILU) v = v * (1.f/(1.f + __expf(-v)));
        const long idx = (tb + r)*(long)O + o;
        if (RES) v += res[idx];
        if (STATS){ ts += v; ts2 += v*v; }
        if (OUTB) outB[idx] = f2b(v); else outF[idx] = v;
      }
    }
    if (STATS){
      const int ol = wo + j*16 + cc;
      atomicAdd(&sb[ol][0], ts);
      atomicAdd(&sb[ol][1], ts2);
    }
  }
  if (STATS){
    __syncthreads();
    if (tid < 16){
      float u=0.f, u2=0.f;
      #pragma unroll
      for (int j2=0;j2<8;j2++){ u += sb[tid*8+j2][0]; u2 += sb[tid*8+j2][1]; }
      const int bb = (int)(t0>>13);
      atomicAdd(&stat[(bb*32 + (o0>>3) + tid)*2],   u);
      atomicAdd(&stat[(bb*32 + (o0>>3) + tid)*2+1], u2);
    }
  }
}

// ---------------- ctx partials + per-block ksum partial; no atomics ----------------
// part row stride 8448: [0,8192) ctx partial at [e*256 + c], [8192,8448) ksum partial
__global__ __launch_bounds__(256,2) void k_ctx(const u16* __restrict__ kvp, float* __restrict__ part,
                      int stride, int koff, int voff){
  const int tid = threadIdx.x;
  const int b = blockIdx.x >> 6, seg = blockIdx.x & 63;
  const int h = tid>>5, d = tid&31;
  __shared__ u16 kb[16][256];
  __shared__ float vf[16][260];
  float acc[32];
  #pragma unroll
  for (int e=0;e<32;e++) acc[e]=0.f;
  float ks = 0.f;
  const long rb = ((long)b*8192 + seg*128)*stride;
  const int w = tid>>6, sub = tid&63;
  for (int tc=0; tc<128; tc+=16){
    #pragma unroll
    for (int p=0;p<4;p++){
      const int row = p*4 + w;
      const long rowbase = rb + (long)(tc+row)*stride;
      if (sub < 32){
        uint4 val = *(const uint4*)(kvp + rowbase + koff + sub*8);
        *(uint4*)&kb[row][sub*8] = val;
      } else {
        const int s2 = sub-32;
        uint4 val = *(const uint4*)(kvp + rowbase + voff + s2*8);
        const u16* vs = (const u16*)&val;
        float4 f0 = {b2f(vs[0]),b2f(vs[1]),b2f(vs[2]),b2f(vs[3])};
        float4 f1 = {b2f(vs[4]),b2f(vs[5]),b2f(vs[6]),b2f(vs[7])};
        *(float4*)&vf[row][s2*8] = f0;
        *(float4*)&vf[row][s2*8+4] = f1;
      }
    }
    __syncthreads();
    #pragma unroll
    for (int r=0;r<16;r++){
      const float kpv = __expf(b2f(kb[r][h*32+d]));
      ks += kpv;
      #pragma unroll
      for (int e4=0;e4<8;e4++){
        const float4 v4 = *(const float4*)&vf[r][h*32+e4*4];
        acc[e4*4+0] += kpv*v4.x; acc[e4*4+1] += kpv*v4.y;
        acc[e4*4+2] += kpv*v4.z; acc[e4*4+3] += kpv*v4.w;
      }
    }
    __syncthreads();
  }
  float* pb = part + (long)blockIdx.x*8448;
  #pragma unroll
  for (int e=0;e<32;e++) pb[e*256 + tid] = acc[e];
  pb[8192 + tid] = ks;
}

// ---------------- reduce ctx partials (raw) + ksum partials ----------------
__global__ void k_ctxred(const float* __restrict__ part, float* __restrict__ ctx,
                         float* __restrict__ ksumF){
  if (blockIdx.x >= 256){
    const int j = (blockIdx.x-256)*256 + threadIdx.x;  // 0..511
    #pragma unroll
    for (int q=0;q<4;q++){
      const int idx = j*4+q;                           // 0..2047
      const int b = idx>>8, cch = idx&255;
      float s=0.f;
      for (int g=0; g<64; g++) s += part[((long)(b*64+g))*8448 + 8192 + cch];
      ksumF[idx] = s;
    }
    return;
  }
  const int i = blockIdx.x*256 + threadIdx.x;
  const int b = i>>13, r = i&8191;
  float s=0.f;
  for (int g=0; g<64; g++) s += part[((long)(b*64+g))*8448 + r];
  ctx[i] = s;
}

// ---------------- attn out: normalize ctx by ksum at staging, then q-softmax contraction ----
__global__ void k_attnout(const u16* __restrict__ q, const float* __restrict__ ctx,
                          const float* __restrict__ ksumF,
                          u16* __restrict__ out, int stride, int qoff){
  const int b = blockIdx.x >> 8, t0 = (blockIdx.x & 255)*32;
  __shared__ float cs[8512];   // [h][d][e] strides 1064/33/1
  for (int i=threadIdx.x; i<8192; i+=256){
    const int e=i>>8, cch=i&255;
    cs[(cch>>5)*1064 + (cch&31)*33 + e] = ctx[(b<<13) + i] / ksumF[b*256 + cch];
  }
  __syncthreads();
  const int t = t0 + (threadIdx.x>>3), h = threadIdx.x&7;
  const u16* qp = q + ((long)b*8192 + t)*stride + qoff + h*32;
  uint4 qv[4];
  #pragma unroll
  for (int j=0;j<4;j++) qv[j] = ((const uint4*)qp)[j];
  const u16* qs = (const u16*)qv;
  float qe[32]; float ssum = 0.f;
  #pragma unroll
  for (int dd=0; dd<32; dd++){ qe[dd] = __expf(b2f(qs[dd])); ssum += qe[dd]; }
  const float inv = 0.17677669529663687f / ssum;   // scale = 32^-0.5
  float o[32];
  #pragma unroll
  for (int e=0;e<32;e++) o[e]=0.f;
  const float* ch = &cs[h*1064];
  #pragma unroll
  for (int dd=0; dd<32; dd++){
    const float w = qe[dd]*inv;
    #pragma unroll
    for (int e=0;e<32;e++) o[e] += w * ch[dd*33+e];
  }
  u16 ob[32];
  #pragma unroll
  for (int e=0;e<32;e++) ob[e] = f2b(o[e]);
  uint4* op = (uint4*)(out + ((long)b*8192 + t)*256 + h*32);
  const uint4* obv = (const uint4*)ob;
  #pragma unroll
  for (int j=0;j<4;j++) op[j] = obv[j];
}

// ---------------- x_new = GN(conv)*g+b + x (in-place) + fused stats of x_new ----------------
__global__ void k_gnres(const u16* __restrict__ conv, float* __restrict__ xr,
                        const float* __restrict__ sums_in, float* __restrict__ sums_out,
                        const float* __restrict__ g, const float* __restrict__ bt){
  const int blk = blockIdx.x;
  const int b = blk>>7;
  const long base = (long)blk*4096;
  const int tid = threadIdx.x;
  const int c0 = (tid<<2)&255;
  const int gr = c0>>3;
  const float s = sums_in[(b*32+gr)*2], s2 = sums_in[(b*32+gr)*2+1];
  const float mu = s*(1.f/65536.f);
  const float rs = rsqrtf(s2*(1.f/65536.f) - mu*mu + 1e-5f);
  float gg[4], bb[4];
  #pragma unroll
  for (int j=0;j<4;j++){ gg[j] = g[c0+j]*rs; bb[j] = bt[c0+j] - mu*gg[j]; }
  float ts=0.f, ts2=0.f;
  for (int it=0; it<16; ++it){
    const long i4 = base + it*256 + tid;
    ushort4 cv = ((const ushort4*)conv)[i4];
    float4 rv = ((const float4*)xr)[i4];
    float ci[4] = {b2f(cv.x),b2f(cv.y),b2f(cv.z),b2f(cv.w)};
    float ri[4] = {rv.x,rv.y,rv.z,rv.w};
    float ov[4];
    #pragma unroll
    for (int j=0;j<4;j++){
      ov[j] = ci[j]*gg[j] + bb[j] + ri[j];
      ts += ov[j]; ts2 += ov[j]*ov[j];
    }
    float4 o4 = {ov[0],ov[1],ov[2],ov[3]};
    ((float4*)xr)[i4] = o4;
  }
  __shared__ float grp[32][2];
  if (tid<32){ grp[tid][0]=0.f; grp[tid][1]=0.f; }
  __syncthreads();
  atomicAdd(&grp[gr][0], ts);
  atomicAdd(&grp[gr][1], ts2);
  __syncthreads();
  if (tid<32){
    atomicAdd(&sums_out[(b*32+tid)*2],   grp[tid][0]);
    atomicAdd(&sums_out[(b*32+tid)*2+1], grp[tid][1]);
  }
}

// ---------------- bf16 normalized copy: h = GN(x)*g+b ----------------
__global__ void k_gnapply(const float* __restrict__ x, u16* __restrict__ o,
                          const float* __restrict__ sums, const float* __restrict__ g,
                          const float* __restrict__ bt){
  const long i4 = (long)blockIdx.x*256 + threadIdx.x;
  const int b = (int)(i4 >> 19);
  const int c0 = (int)((i4<<2) & 255);
  float4 v = ((const float4*)x)[i4];
  float vi[4] = {v.x,v.y,v.z,v.w};
  u16 obi[4];
  #pragma unroll
  for (int j=0;j<4;j++){
    const int c = c0+j, gr=c>>3;
    const float s = sums[(b*32+gr)*2], s2 = sums[(b*32+gr)*2+1];
    const float mu = s*(1.f/65536.f);
    const float rs = rsqrtf(s2*(1.f/65536.f)-mu*mu+1e-5f);
    obi[j] = f2b((vi[j]-mu)*rs*g[c]+bt[c]);
  }
  ushort4 ob; ob.x=obi[0]; ob.y=obi[1]; ob.z=obi[2]; ob.w=obi[3];
  ((ushort4*)o)[i4] = ob;
}

// ---------------- final transpose [B,T,256] -> [B,256,T] ----------------
__global__ void k_final(const float* __restrict__ y, float* __restrict__ out){
  const int b = blockIdx.z;
  const int t0 = blockIdx.x*64, c0 = blockIdx.y*64;
  __shared__ float tile[64][65];
  #pragma unroll
  for (int p=0;p<4;p++){
    const int tt = (threadIdx.x>>4) + p*16, c4 = (threadIdx.x&15)*4;
    const float4 v = *(const float4*)&y[((long)b*8192 + t0+tt)*256 + c0+c4];
    tile[c4+0][tt]=v.x; tile[c4+1][tt]=v.y; tile[c4+2][tt]=v.z; tile[c4+3][tt]=v.w;
  }
  __syncthreads();
  #pragma unroll
  for (int p=0;p<4;p++){
    const int cc = (threadIdx.x>>4) + p*16, t4 = (threadIdx.x&15)*4;
    float4 v = {tile[cc][t4], tile[cc][t4+1], tile[cc][t4+2], tile[cc][t4+3]};
    *(float4*)&out[((long)b*256 + c0+cc)*8192 + t0+t4] = v;
  }
}

extern "C" void kernel_launch(void* const* d_in, const int* in_sizes, int n_in,
                              void* d_out, int out_size, void* d_ws, size_t ws_size,
                              hipStream_t stream){
  (void)in_sizes; (void)n_in; (void)out_size; (void)ws_size;
  const float* x   = (const float*)d_in[0];
  const float* c   = (const float*)d_in[1];
  const float* W_qkv=(const float*)d_in[2];
  const float* W_so =(const float*)d_in[3];
  const float* b_so =(const float*)d_in[4];
  const float* sa_g =(const float*)d_in[5];
  const float* sa_b =(const float*)d_in[6];
  const float* W_cq =(const float*)d_in[7];
  const float* W_ckv=(const float*)d_in[8];
  const float* W_co =(const float*)d_in[9];
  const float* b_co =(const float*)d_in[10];
  const float* ca_g =(const float*)d_in[11];
  const float* ca_b =(const float*)d_in[12];
  const float* W_m1 =(const float*)d_in[13];
  const float* b_m1 =(const float*)d_in[14];
  const float* W_m2 =(const float*)d_in[15];
  const float* b_m2 =(const float*)d_in[16];
  const float* nm_g =(const float*)d_in[17];
  const float* nm_b =(const float*)d_in[18];
  const float* nm1_g=(const float*)d_in[19];
  const float* nm1_b=(const float*)d_in[20];
  const float* nm2_g=(const float*)d_in[21];
  const float* nm2_b=(const float*)d_in[22];
  const float* nm3_g=(const float*)d_in[23];
  const float* nm3_b=(const float*)d_in[24];
  float* out = (float*)d_out;

  char* ws = (char*)d_ws;
  const size_t MB = 1024ull*1024ull;
  u16* wbf  = (u16*)ws;
  u16* wQKV = wbf;
  u16* wSO  = wbf + 196608;
  u16* wCQ  = wbf + 262144;
  u16* wCKV = wbf + 327680;
  u16* wCO  = wbf + 589824;
  u16* wM1  = wbf + 655360;
  u16* wM2  = wbf + 819200;
  float* stats = (float*)(ws + 2*MB);
  float* xstat = stats;
  float* cstat = stats + 512;
  float* so_sum= stats + 1024;
  float* x1_sum= stats + 1536;
  float* co_sum= stats + 2048;
  float* x2_sum= stats + 2560;
  float* ksumF = stats + 3072;            // 2048 floats
  float* ctxb  = stats + 8192;            // 65536 floats
  float* xT    = (float*)(ws + 4*MB);     // [65536,256] fp32 residual stream (in-place)
  u16*   hbf   = (u16*)(ws + 68*MB);      // [65536,256] bf16 normalized   (aliased: part)
  float* part  = (float*)(ws + 68*MB);    // [512][8448] fp32 partials (17.3MB) — alias of hbf
  u16*   cnbf  = (u16*)(ws + 100*MB);     // [65536,512] bf16 normalized c
  u16*   qkvb  = (u16*)(ws + 164*MB);     // [65536,768] bf16 (reused: cross-q, mlp hidden)
  u16*   kvb   = (u16*)(ws + 264*MB);     // [65536,512] bf16 cross kv (aliased: convb, convF)
  u16*   convb = (u16*)(ws + 264*MB);     // [65536,256] bf16 conv out (stages 1-2)
  float* convF = (float*)(ws + 264*MB);   // [65536,256] fp32 conv out (stage 3)
  u16*   attno = (u16*)(ws + 328*MB);     // [65536,256] bf16

  k_zero<<<12,256,0,stream>>>(stats+1024, 3072-1024+1024); // zero so/x1/co/x2 sums (stats[1024..4096))
  k_cvtall<<<3840,256,0,stream>>>(W_qkv, W_so, W_cq, W_ckv, W_co, W_m1, W_m2, wbf);

  // ---- stage 1: self linear attention ----
  k_stats_ct<<<512,256,0,stream>>>(x, c, xstat, cstat);
  k_trans<true ><<<dim3(128,4,8),256,0,stream>>>(x, xT, hbf, xstat, nm_g, nm_b, 256, 3);
  k_trans<false><<<dim3(128,8,8),256,0,stream>>>(c, nullptr, cnbf, cstat, nm3_g, nm3_b, 512, 4);
  k_gemm<true,false,false,false,false><<<dim3(6,512),256,0,stream>>>(hbf, wQKV, nullptr, qkvb, nullptr, nullptr, nullptr, 256, 768);
  k_ctx<<<512,256,0,stream>>>(qkvb, part, 768, 256, 512);
  k_ctxred<<<258,256,0,stream>>>(part, ctxb, ksumF);
  k_attnout<<<2048,256,0,stream>>>(qkvb, ctxb, ksumF, attno, 768, 0);
  k_gemm<true,true,false,false,true><<<dim3(2,512),256,0,stream>>>(attno, wSO, nullptr, convb, b_so, nullptr, so_sum, 256, 256);
  k_gnres<<<1024,256,0,stream>>>(convb, xT, so_sum, x1_sum, sa_g, sa_b);

  // ---- stage 2: cross linear attention ----
  k_gnapply<<<16384,256,0,stream>>>(xT, hbf, x1_sum, nm1_g, nm1_b);
  k_gemm<true,false,false,false,false><<<dim3(2,512),256,0,stream>>>(hbf, wCQ, nullptr, qkvb, nullptr, nullptr, nullptr, 256, 256);
  k_gemm<true,false,false,false,false><<<dim3(4,512),256,0,stream>>>(cnbf, wCKV, nullptr, kvb, nullptr, nullptr, nullptr, 512, 512);
  k_ctx<<<512,256,0,stream>>>(kvb, part, 512, 0, 256);
  k_ctxred<<<258,256,0,stream>>>(part, ctxb, ksumF);
  k_attnout<<<2048,256,0,stream>>>(qkvb, ctxb, ksumF, attno, 256, 0);
  k_gemm<true,true,false,false,true><<<dim3(2,512),256,0,stream>>>(attno, wCO, nullptr, convb, b_co, nullptr, co_sum, 256, 256);
  k_gnres<<<1024,256,0,stream>>>(convb, xT, co_sum, x2_sum, ca_g, ca_b);

  // ---- stage 3: SiLU MLP ----
  k_gnapply<<<16384,256,0,stream>>>(xT, hbf, x2_sum, nm2_g, nm2_b);
  k_gemm<true,true,true,false,false><<<dim3(5,512),256,0,stream>>>(hbf, wM1, nullptr, qkvb, b_m1, nullptr, nullptr, 256, 640);
  k_gemm<false,true,false,true,false><<<dim3(2,512),256,0,stream>>>(qkvb, wM2, convF, nullptr, b_m2, xT, nullptr, 640, 256);
  k_final<<<dim3(128,4,8),256,0,stream>>>(convF, out);
}

// Round 4
// 977.340 us; speedup vs baseline: 1.4407x; 1.0683x over previous
//
#include <hip/hip_runtime.h>
#include <cmath>

typedef unsigned short u16;
typedef __attribute__((ext_vector_type(8))) __bf16 bf16x8;
typedef __attribute__((ext_vector_type(4))) float f32x4;

#define DEV static __device__ __forceinline__

DEV float b2f(u16 u){ union{unsigned i; float f;} v; v.i=((unsigned)u)<<16; return v.f; }
DEV u16 f2b(float f){ union{float f; unsigned i;} v; v.f=f; unsigned r = v.i + 0x7FFFu + ((v.i>>16)&1u); return (u16)(r>>16); }

#define GLL(g,l) __builtin_amdgcn_global_load_lds((const __attribute__((address_space(1))) void*)(g), (__attribute__((address_space(3))) void*)(l), 16, 0, 0)

// ---------------- tiny utility kernels ----------------
__global__ void k_zero(float* p, int n){ int i = blockIdx.x*256+threadIdx.x; if(i<n) p[i]=0.f; }

__global__ void k_cvtall(const float* __restrict__ s0,const float* __restrict__ s1,
                         const float* __restrict__ s2,const float* __restrict__ s3,
                         const float* __restrict__ s4,const float* __restrict__ s5,
                         const float* __restrict__ s6, u16* __restrict__ d){
  int i = blockIdx.x*256 + threadIdx.x;
  if (i >= 983040) return;
  const float* s; int off;
  if      (i < 196608){ s=s0; off=0; }
  else if (i < 262144){ s=s1; off=196608; }
  else if (i < 327680){ s=s2; off=262144; }
  else if (i < 589824){ s=s3; off=327680; }
  else if (i < 655360){ s=s4; off=589824; }
  else if (i < 819200){ s=s5; off=655360; }
  else                { s=s6; off=819200; }
  d[i] = f2b(s[i-off]);
}

// ---------------- GN raw sums, balanced: 6144 blocks x 32KB, atomic partials ----------------
__global__ void k_stats2(const float* __restrict__ x, const float* __restrict__ c,
                         float* __restrict__ statx, float* __restrict__ statc){
  const int blk = blockIdx.x;
  const float* src; float* stat; long base; int chunk;
  if (blk < 2048){ chunk = blk>>3; base = (long)chunk*65536 + (long)(blk&7)*8192; src=x; stat=statx; }
  else { const int b2 = blk-2048; chunk = b2>>4; base = (long)chunk*131072 + (long)(b2&15)*8192; src=c; stat=statc; }
  const float4* xp = (const float4*)(src+base);
  float s=0.f, s2=0.f;
  #pragma unroll
  for (int i=0;i<8;i++){
    float4 v = xp[i*256 + threadIdx.x];
    s  += v.x+v.y+v.z+v.w;
    s2 += v.x*v.x+v.y*v.y+v.z*v.z+v.w*v.w;
  }
  __shared__ float a[256], a2[256];
  a[threadIdx.x]=s; a2[threadIdx.x]=s2;
  __syncthreads();
  for (int off=128; off>0; off>>=1){
    if (threadIdx.x < off){ a[threadIdx.x]+=a[threadIdx.x+off]; a2[threadIdx.x]+=a2[threadIdx.x+off]; }
    __syncthreads();
  }
  if (threadIdx.x==0){
    atomicAdd(&stat[chunk*2],   a[0]);
    atomicAdd(&stat[chunk*2+1], a2[0]);
  }
}

// ---------------- transpose [B,C,T] -> [B,T,C]; normalized bf16 (+ optionally raw bf16) ----
template<bool WRAW>
__global__ void k_trans(const float* __restrict__ src, u16* __restrict__ dstRaw,
                        u16* __restrict__ dstB, const float* __restrict__ stat,
                        const float* __restrict__ gw, const float* __restrict__ bw,
                        int C, int chsh, float inv_n){
  const int b = blockIdx.z;
  const int t0 = blockIdx.x*64, c0 = blockIdx.y*64;
  __shared__ float tile[64][65];
  #pragma unroll
  for (int p=0;p<4;p++){
    const int cc = (threadIdx.x>>4) + p*16, tt = (threadIdx.x&15)*4;
    const float4 v = *(const float4*)&src[((long)b*C + c0+cc)*8192 + t0+tt];
    tile[cc][tt+0]=v.x; tile[cc][tt+1]=v.y; tile[cc][tt+2]=v.z; tile[cc][tt+3]=v.w;
  }
  __syncthreads();
  #pragma unroll
  for (int p=0;p<4;p++){
    const int tt = (threadIdx.x>>4) + p*16, c4 = (threadIdx.x&15)*4;
    u16 nbi[4], rbi[4];
    #pragma unroll
    for (int j=0;j<4;j++){
      const float raw = tile[c4+j][tt];
      const int ch = c0+c4+j, gr = ch>>chsh;
      const float s = stat[(b*32+gr)*2], s2 = stat[(b*32+gr)*2+1];
      const float mu = s*inv_n;
      const float rs = rsqrtf(s2*inv_n - mu*mu + 1e-5f);
      nbi[j] = f2b((raw-mu)*rs*gw[ch]+bw[ch]);
      rbi[j] = f2b(raw);
    }
    const long db = ((long)b*8192 + t0+tt)*C + c0+c4;
    ushort4 nb; nb.x=nbi[0]; nb.y=nbi[1]; nb.z=nbi[2]; nb.w=nbi[3];
    *(ushort4*)&dstB[db] = nb;
    if (WRAW){ ushort4 rv; rv.x=rbi[0]; rv.y=rbi[1]; rv.z=rbi[2]; rv.w=rbi[3]; *(ushort4*)&dstRaw[db] = rv; }
  }
}

// ---------------- MFMA GEMM: out[t,o] = sum_k A[t,k]*W[o,k] ----------------
// SPLIT: output segments of 256 cols each go to consecutive 2^24-element buffers
template<bool OUTB, bool BIAS, bool SILU, bool RES, bool STATS, bool SPLIT>
__global__ __launch_bounds__(256,2) void k_gemm(
    const u16* __restrict__ A, const u16* __restrict__ W,
    float* __restrict__ outF, u16* __restrict__ outB,
    const float* __restrict__ bias, const u16* __restrict__ res,
    float* __restrict__ stat, int K, int O)
{
  __shared__ u16 As[128*64];
  __shared__ u16 Ws[128*64];
  __shared__ float sb[128][2];
  const int tid = threadIdx.x;
  const int wv = tid>>6, lane = tid&63;
  const long t0 = (long)blockIdx.y*128;
  const int o0 = blockIdx.x*128;
  const int wt = (wv>>1)*64, wo = (wv&1)*64;
  const int lr = lane>>3, lc = (lane&7)*8;
  f32x4 acc[4][4] = {};
  for (int kc = 0; kc < K; kc += 64){
    #pragma unroll
    for (int it = 0; it < 4; ++it){
      const int r = wv*32 + it*8;
      GLL(A + (t0 + r + lr)*(long)K + kc + lc, &As[r*64]);
      GLL(W + (long)(o0 + r + lr)*K + kc + lc, &Ws[r*64]);
    }
    __syncthreads();
    #pragma unroll
    for (int ks=0; ks<2; ++ks){
      const int kb = ks*32 + (lane>>4)*8;
      bf16x8 af[4], bfr[4];
      #pragma unroll
      for (int i=0;i<4;i++) af[i]  = *(const bf16x8*)&As[(wt + i*16 + (lane&15))*64 + kb];
      #pragma unroll
      for (int j=0;j<4;j++) bfr[j] = *(const bf16x8*)&Ws[(wo + j*16 + (lane&15))*64 + kb];
      #pragma unroll
      for (int i=0;i<4;i++)
        #pragma unroll
        for (int j=0;j<4;j++)
          acc[i][j] = __builtin_amdgcn_mfma_f32_16x16x32_bf16(af[i], bfr[j], acc[i][j], 0, 0, 0);
    }
    __syncthreads();
  }
  if (STATS){
    if (tid < 128){ sb[tid][0]=0.f; sb[tid][1]=0.f; }
    __syncthreads();
  }
  const int q = lane>>4, cc = lane&15;
  #pragma unroll
  for (int j=0;j<4;j++){
    const int o = o0 + wo + j*16 + cc;
    const float bv = BIAS ? bias[o] : 0.f;
    float ts=0.f, ts2=0.f;
    #pragma unroll
    for (int i=0;i<4;i++){
      const long tb = t0 + wt + i*16 + q*4;
      #pragma unroll
      for (int r=0;r<4;r++){
        float v = acc[i][j][r] + bv;
        if (SILU) v = v * (1.f/(1.f + __expf(-v)));
        long idx;
        if (SPLIT) idx = ((long)(o>>8)<<24) + (tb + r)*256 + (o&255);
        else       idx = (tb + r)*(long)O + o;
        if (RES) v += b2f(res[idx]);
        if (STATS){ ts += v; ts2 += v*v; }
        if (OUTB) outB[idx] = f2b(v); else outF[idx] = v;
      }
    }
    if (STATS){
      const int ol = wo + j*16 + cc;
      atomicAdd(&sb[ol][0], ts);
      atomicAdd(&sb[ol][1], ts2);
    }
  }
  if (STATS){
    __syncthreads();
    if (tid < 16){
      float u=0.f, u2=0.f;
      #pragma unroll
      for (int j2=0;j2<8;j2++){ u += sb[tid*8+j2][0]; u2 += sb[tid*8+j2][1]; }
      const int bb = (int)(t0>>13);
      atomicAdd(&stat[(bb*32 + (o0>>3) + tid)*2],   u);
      atomicAdd(&stat[(bb*32 + (o0>>3) + tid)*2+1], u2);
    }
  }
}

// ---------------- ctx partials + per-block ksum partial; dense [65536,256] k/v inputs ----------------
__global__ __launch_bounds__(256,2) void k_ctx(const u16* __restrict__ kp, const u16* __restrict__ vp,
                                               float* __restrict__ part){
  const int tid = threadIdx.x;
  const int b = blockIdx.x >> 6, seg = blockIdx.x & 63;
  const int h = tid>>5, d = tid&31;
  __shared__ u16 kb[16][256];
  __shared__ float vf[16][260];
  float acc[32];
  #pragma unroll
  for (int e=0;e<32;e++) acc[e]=0.f;
  float ks = 0.f;
  const long rb = (long)b*8192 + seg*128;
  const int w = tid>>6, sub = tid&63;
  for (int tc=0; tc<128; tc+=16){
    #pragma unroll
    for (int p=0;p<4;p++){
      const int row = p*4 + w;
      const long rowbase = (rb + tc + row)*256;
      if (sub < 32){
        uint4 val = *(const uint4*)(kp + rowbase + sub*8);
        *(uint4*)&kb[row][sub*8] = val;
      } else {
        const int s2 = sub-32;
        uint4 val = *(const uint4*)(vp + rowbase + s2*8);
        const u16* vs = (const u16*)&val;
        float4 f0 = {b2f(vs[0]),b2f(vs[1]),b2f(vs[2]),b2f(vs[3])};
        float4 f1 = {b2f(vs[4]),b2f(vs[5]),b2f(vs[6]),b2f(vs[7])};
        *(float4*)&vf[row][s2*8] = f0;
        *(float4*)&vf[row][s2*8+4] = f1;
      }
    }
    __syncthreads();
    #pragma unroll
    for (int r=0;r<16;r++){
      const float kpv = __expf(b2f(kb[r][h*32+d]));
      ks += kpv;
      #pragma unroll
      for (int e4=0;e4<8;e4++){
        const float4 v4 = *(const float4*)&vf[r][h*32+e4*4];
        acc[e4*4+0] += kpv*v4.x; acc[e4*4+1] += kpv*v4.y;
        acc[e4*4+2] += kpv*v4.z; acc[e4*4+3] += kpv*v4.w;
      }
    }
    __syncthreads();
  }
  float* pb = part + (long)blockIdx.x*8448;
  #pragma unroll
  for (int e=0;e<32;e++) pb[e*256 + tid] = acc[e];
  pb[8192 + tid] = ks;
}

// ---------------- reduce ctx partials + ksum partials ----------------
__global__ void k_ctxred(const float* __restrict__ part, float* __restrict__ ctx,
                         float* __restrict__ ksumF){
  if (blockIdx.x >= 256){
    const int j = (blockIdx.x-256)*256 + threadIdx.x;
    #pragma unroll
    for (int q=0;q<4;q++){
      const int idx = j*4+q;
      const int b = idx>>8, cch = idx&255;
      float s=0.f;
      for (int g=0; g<64; g++) s += part[((long)(b*64+g))*8448 + 8192 + cch];
      ksumF[idx] = s;
    }
    return;
  }
  const int i = blockIdx.x*256 + threadIdx.x;
  const int b = i>>13, r = i&8191;
  float s=0.f;
  for (int g=0; g<64; g++) s += part[((long)(b*64+g))*8448 + r];
  ctx[i] = s;
}

// ---------------- attn out: q-softmax contraction against ctx/ksum; q dense [65536,256] ----
__global__ void k_attnout(const u16* __restrict__ q, const float* __restrict__ ctx,
                          const float* __restrict__ ksumF, u16* __restrict__ out){
  const int b = blockIdx.x >> 8, t0 = (blockIdx.x & 255)*32;
  __shared__ float cs[8512];   // [h][d][e] strides 1064/33/1
  for (int i=threadIdx.x; i<8192; i+=256){
    const int e=i>>8, cch=i&255;
    cs[(cch>>5)*1064 + (cch&31)*33 + e] = ctx[(b<<13) + i] / ksumF[b*256 + cch];
  }
  __syncthreads();
  const int t = t0 + (threadIdx.x>>3), h = threadIdx.x&7;
  const u16* qp = q + ((long)b*8192 + t)*256 + h*32;
  uint4 qv[4];
  #pragma unroll
  for (int j=0;j<4;j++) qv[j] = ((const uint4*)qp)[j];
  const u16* qs = (const u16*)qv;
  float qe[32]; float ssum = 0.f;
  #pragma unroll
  for (int dd=0; dd<32; dd++){ qe[dd] = __expf(b2f(qs[dd])); ssum += qe[dd]; }
  const float inv = 0.17677669529663687f / ssum;
  float o[32];
  #pragma unroll
  for (int e=0;e<32;e++) o[e]=0.f;
  const float* ch = &cs[h*1064];
  #pragma unroll
  for (int dd=0; dd<32; dd++){
    const float w = qe[dd]*inv;
    #pragma unroll
    for (int e=0;e<32;e++) o[e] += w * ch[dd*33+e];
  }
  u16 ob[32];
  #pragma unroll
  for (int e=0;e<32;e++) ob[e] = f2b(o[e]);
  uint4* op = (uint4*)(out + ((long)b*8192 + t)*256 + h*32);
  const uint4* obv = (const uint4*)ob;
  #pragma unroll
  for (int j=0;j<4;j++) op[j] = obv[j];
}

// ---------------- x_new = GN(conv)*g+b + x (bf16 residual, in-place) + stats of x_new ----------------
__global__ void k_gnres(const u16* __restrict__ conv, u16* __restrict__ xr,
                        const float* __restrict__ sums_in, float* __restrict__ sums_out,
                        const float* __restrict__ g, const float* __restrict__ bt){
  const int blk = blockIdx.x;
  const int b = blk>>7;
  const long base = (long)blk*4096;
  const int tid = threadIdx.x;
  const int c0 = (tid<<2)&255;
  const int gr = c0>>3;
  const float s = sums_in[(b*32+gr)*2], s2 = sums_in[(b*32+gr)*2+1];
  const float mu = s*(1.f/65536.f);
  const float rs = rsqrtf(s2*(1.f/65536.f) - mu*mu + 1e-5f);
  float gg[4], bb[4];
  #pragma unroll
  for (int j=0;j<4;j++){ gg[j] = g[c0+j]*rs; bb[j] = bt[c0+j] - mu*gg[j]; }
  float ts=0.f, ts2=0.f;
  for (int it=0; it<16; ++it){
    const long i4 = base + it*256 + tid;
    ushort4 cv = ((const ushort4*)conv)[i4];
    ushort4 rv = ((const ushort4*)xr)[i4];
    float ov[4];
    const float ci[4] = {b2f(cv.x),b2f(cv.y),b2f(cv.z),b2f(cv.w)};
    const float ri[4] = {b2f(rv.x),b2f(rv.y),b2f(rv.z),b2f(rv.w)};
    #pragma unroll
    for (int j=0;j<4;j++){
      ov[j] = ci[j]*gg[j] + bb[j] + ri[j];
      ts += ov[j]; ts2 += ov[j]*ov[j];
    }
    ushort4 o4; o4.x=f2b(ov[0]); o4.y=f2b(ov[1]); o4.z=f2b(ov[2]); o4.w=f2b(ov[3]);
    ((ushort4*)xr)[i4] = o4;
  }
  __shared__ float grp[32][2];
  if (tid<32){ grp[tid][0]=0.f; grp[tid][1]=0.f; }
  __syncthreads();
  atomicAdd(&grp[gr][0], ts);
  atomicAdd(&grp[gr][1], ts2);
  __syncthreads();
  if (tid<32){
    atomicAdd(&sums_out[(b*32+tid)*2],   grp[tid][0]);
    atomicAdd(&sums_out[(b*32+tid)*2+1], grp[tid][1]);
  }
}

// ---------------- bf16 normalized copy: h = GN(x)*g+b (bf16 in/out) ----------------
__global__ void k_gnapply(const u16* __restrict__ x, u16* __restrict__ o,
                          const float* __restrict__ sums, const float* __restrict__ g,
                          const float* __restrict__ bt){
  const long i4 = (long)blockIdx.x*256 + threadIdx.x;
  const int b = (int)(i4 >> 19);
  const int c0 = (int)((i4<<2) & 255);
  ushort4 v = ((const ushort4*)x)[i4];
  const float vi[4] = {b2f(v.x),b2f(v.y),b2f(v.z),b2f(v.w)};
  u16 obi[4];
  #pragma unroll
  for (int j=0;j<4;j++){
    const int ch = c0+j, gr=ch>>3;
    const float s = sums[(b*32+gr)*2], s2 = sums[(b*32+gr)*2+1];
    const float mu = s*(1.f/65536.f);
    const float rs = rsqrtf(s2*(1.f/65536.f)-mu*mu+1e-5f);
    obi[j] = f2b((vi[j]-mu)*rs*g[ch]+bt[ch]);
  }
  ushort4 ob; ob.x=obi[0]; ob.y=obi[1]; ob.z=obi[2]; ob.w=obi[3];
  ((ushort4*)o)[i4] = ob;
}

// ---------------- final transpose [B,T,256] -> [B,256,T] ----------------
__global__ void k_final(const float* __restrict__ y, float* __restrict__ out){
  const int b = blockIdx.z;
  const int t0 = blockIdx.x*64, c0 = blockIdx.y*64;
  __shared__ float tile[64][65];
  #pragma unroll
  for (int p=0;p<4;p++){
    const int tt = (threadIdx.x>>4) + p*16, c4 = (threadIdx.x&15)*4;
    const float4 v = *(const float4*)&y[((long)b*8192 + t0+tt)*256 + c0+c4];
    tile[c4+0][tt]=v.x; tile[c4+1][tt]=v.y; tile[c4+2][tt]=v.z; tile[c4+3][tt]=v.w;
  }
  __syncthreads();
  #pragma unroll
  for (int p=0;p<4;p++){
    const int cc = (threadIdx.x>>4) + p*16, t4 = (threadIdx.x&15)*4;
    float4 v = {tile[cc][t4], tile[cc][t4+1], tile[cc][t4+2], tile[cc][t4+3]};
    *(float4*)&out[((long)b*256 + c0+cc)*8192 + t0+t4] = v;
  }
}

extern "C" void kernel_launch(void* const* d_in, const int* in_sizes, int n_in,
                              void* d_out, int out_size, void* d_ws, size_t ws_size,
                              hipStream_t stream){
  (void)in_sizes; (void)n_in; (void)out_size; (void)ws_size;
  const float* x   = (const float*)d_in[0];
  const float* c   = (const float*)d_in[1];
  const float* W_qkv=(const float*)d_in[2];
  const float* W_so =(const float*)d_in[3];
  const float* b_so =(const float*)d_in[4];
  const float* sa_g =(const float*)d_in[5];
  const float* sa_b =(const float*)d_in[6];
  const float* W_cq =(const float*)d_in[7];
  const float* W_ckv=(const float*)d_in[8];
  const float* W_co =(const float*)d_in[9];
  const float* b_co =(const float*)d_in[10];
  const float* ca_g =(const float*)d_in[11];
  const float* ca_b =(const float*)d_in[12];
  const float* W_m1 =(const float*)d_in[13];
  const float* b_m1 =(const float*)d_in[14];
  const float* W_m2 =(const float*)d_in[15];
  const float* b_m2 =(const float*)d_in[16];
  const float* nm_g =(const float*)d_in[17];
  const float* nm_b =(const float*)d_in[18];
  const float* nm1_g=(const float*)d_in[19];
  const float* nm1_b=(const float*)d_in[20];
  const float* nm2_g=(const float*)d_in[21];
  const float* nm2_b=(const float*)d_in[22];
  const float* nm3_g=(const float*)d_in[23];
  const float* nm3_b=(const float*)d_in[24];
  float* out = (float*)d_out;

  char* ws = (char*)d_ws;
  const size_t MB = 1024ull*1024ull;
  u16* wbf  = (u16*)ws;
  u16* wQKV = wbf;
  u16* wSO  = wbf + 196608;
  u16* wCQ  = wbf + 262144;
  u16* wCKV = wbf + 327680;
  u16* wCO  = wbf + 589824;
  u16* wM1  = wbf + 655360;
  u16* wM2  = wbf + 819200;
  float* stats = (float*)(ws + 2*MB);
  float* xstat = stats;           // raw sums (512)
  float* cstat = stats + 512;     // raw sums (512)
  float* so_sum= stats + 1024;
  float* x1_sum= stats + 1536;
  float* co_sum= stats + 2048;
  float* x2_sum= stats + 2560;
  float* ksumF = stats + 3072;    // 2048
  float* ctxb  = stats + 8192;    // 65536
  u16*   xT    = (u16*)(ws + 4*MB);       // [65536,256] bf16 residual stream (in-place)
  u16*   hbf   = (u16*)(ws + 68*MB);      // [65536,256] bf16 normalized (aliased: part)
  float* part  = (float*)(ws + 68*MB);    // [512][8448] fp32 partials — alias of hbf
  u16*   cnbf  = (u16*)(ws + 100*MB);     // [65536,512] bf16 normalized c
  u16*   qkvb  = (u16*)(ws + 164*MB);     // 3 x [65536,256] bf16 (q,k,v; reused: cross-q, mlp hidden)
  u16*   kvb   = (u16*)(ws + 264*MB);     // 2 x [65536,256] bf16 cross k,v (aliased: convb, convF)
  u16*   convb = (u16*)(ws + 264*MB);     // [65536,256] bf16 conv out (stages 1-2)
  float* convF = (float*)(ws + 264*MB);   // [65536,256] fp32 conv out (stage 3)
  u16*   attno = (u16*)(ws + 328*MB);     // [65536,256] bf16
  const long SEG = 1L<<24;

  k_zero<<<12,256,0,stream>>>(stats, 3072);
  k_cvtall<<<3840,256,0,stream>>>(W_qkv, W_so, W_cq, W_ckv, W_co, W_m1, W_m2, wbf);

  // ---- stage 1: self linear attention ----
  k_stats2<<<6144,256,0,stream>>>(x, c, xstat, cstat);
  k_trans<true ><<<dim3(128,4,8),256,0,stream>>>(x, xT, hbf, xstat, nm_g, nm_b, 256, 3, 1.f/65536.f);
  k_trans<false><<<dim3(128,8,8),256,0,stream>>>(c, nullptr, cnbf, cstat, nm3_g, nm3_b, 512, 4, 1.f/131072.f);
  k_gemm<true,false,false,false,false,true><<<dim3(6,512),256,0,stream>>>(hbf, wQKV, nullptr, qkvb, nullptr, nullptr, nullptr, 256, 768);
  k_ctx<<<512,256,0,stream>>>(qkvb+SEG, qkvb+2*SEG, part);
  k_ctxred<<<258,256,0,stream>>>(part, ctxb, ksumF);
  k_attnout<<<2048,256,0,stream>>>(qkvb, ctxb, ksumF, attno);
  k_gemm<true,true,false,false,true,false><<<dim3(2,512),256,0,stream>>>(attno, wSO, nullptr, convb, b_so, nullptr, so_sum, 256, 256);
  k_gnres<<<1024,256,0,stream>>>(convb, xT, so_sum, x1_sum, sa_g, sa_b);

  // ---- stage 2: cross linear attention ----
  k_gnapply<<<16384,256,0,stream>>>(xT, hbf, x1_sum, nm1_g, nm1_b);
  k_gemm<true,false,false,false,false,false><<<dim3(2,512),256,0,stream>>>(hbf, wCQ, nullptr, qkvb, nullptr, nullptr, nullptr, 256, 256);
  k_gemm<true,false,false,false,false,true><<<dim3(4,512),256,0,stream>>>(cnbf, wCKV, nullptr, kvb, nullptr, nullptr, nullptr, 512, 512);
  k_ctx<<<512,256,0,stream>>>(kvb, kvb+SEG, part);
  k_ctxred<<<258,256,0,stream>>>(part, ctxb, ksumF);
  k_attnout<<<2048,256,0,stream>>>(qkvb, ctxb, ksumF, attno);
  k_gemm<true,true,false,false,true,false><<<dim3(2,512),256,0,stream>>>(attno, wCO, nullptr, convb, b_co, nullptr, co_sum, 256, 256);
  k_gnres<<<1024,256,0,stream>>>(convb, xT, co_sum, x2_sum, ca_g, ca_b);

  // ---- stage 3: SiLU MLP ----
  k_gnapply<<<16384,256,0,stream>>>(xT, hbf, x2_sum, nm2_g, nm2_b);
  k_gemm<true,true,true,false,false,false><<<dim3(5,512),256,0,stream>>>(hbf, wM1, nullptr, qkvb, b_m1, nullptr, nullptr, 256, 640);
  k_gemm<false,true,false,true,false,false><<<dim3(2,512),256,0,stream>>>(qkvb, wM2, convF, nullptr, b_m2, xT, nullptr, 640, 256);
  k_final<<<dim3(128,4,8),256,0,stream>>>(convF, out);
}